// Round 1
// baseline (435.485 us; speedup 1.0000x reference)
//
#include <hip/hip_runtime.h>

// Conv4d: x (2,16,20,20,20,20) f32, w (16,32,3,3,3,3) f32 -> out (2,32,18,18,18,18) f32
// Direct conv, LDS-staged per-ic x slab + transposed weights, register-blocked
// 4 oc x 6 l outputs per thread. Compute-bound (fp32 VALU, no fp32 MFMA).

#define BLK 448      // 7 waves
#define ACTIVE 432   // 8 oc-groups * 18 k * 3 l-chunks

// x strides (floats): n 2560000, ic 160000, i 8000, j 400, k 20, l 1
// w strides (floats): ic 2592, oc 81, tap (a*27+b*9+c*3+d) 1
// out strides (floats): n 3359232, oc 104976, i 5832, j 324, k 18, l 1

__global__ __launch_bounds__(BLK) void conv4d_kernel(
    const float* __restrict__ x, const float* __restrict__ w,
    float* __restrict__ out)
{
    __shared__ float lds_x[3600];       // [ab 0..8][k' 0..19][l' 0..19]
    __shared__ float lds_w[81 * 33];    // [tap][oc], stride 33 kills bank conflicts

    const int i = blockIdx.x;
    const int j = blockIdx.y;
    const int n = blockIdx.z;
    const int t = threadIdx.x;

    const bool active = (t < ACTIVE);
    const int tt  = active ? t : 0;
    const int ocb = tt / 54;            // 0..7
    const int kl  = tt % 54;
    const int k   = kl / 3;             // 0..17
    const int l0  = (kl % 3) * 6;       // 0,6,12
    const int oc0 = ocb * 4;

    float acc[4][6];
    #pragma unroll
    for (int u = 0; u < 4; ++u)
        #pragma unroll
        for (int q = 0; q < 6; ++q)
            acc[u][q] = 0.0f;

    const float* xn = x + (size_t)n * 2560000;

    for (int ic = 0; ic < 16; ++ic) {
        __syncthreads();
        // --- stage x slab: 9 runs of 400 contiguous floats, as float4 ---
        {
            const float* xb = xn + ic * 160000 + i * 8000 + j * 400;
            for (int s = t; s < 900; s += BLK) {
                const int ab = s / 100, rem = s % 100;
                const int a = ab / 3, b = ab % 3;
                const float4 v = *(const float4*)(xb + a * 8000 + b * 400 + rem * 4);
                *(float4*)(&lds_x[ab * 400 + rem * 4]) = v;
            }
            // --- stage + transpose weights for this ic: w[ic][oc][tap] -> lds_w[tap*33+oc]
            const float* wb = w + ic * 2592;
            for (int s = t; s < 2592; s += BLK) {
                const int oc = s / 81, tap = s % 81;
                lds_w[tap * 33 + oc] = wb[s];
            }
        }
        __syncthreads();

        // --- compute: 27 taps x (8 x-reads + 12 w-reads + 72 FMA) ---
        #pragma unroll
        for (int ab = 0; ab < 9; ++ab) {
            const float* xab = lds_x + ab * 400 + k * 20 + l0;
            #pragma unroll
            for (int c = 0; c < 3; ++c) {
                const float* xr = xab + c * 20;
                float xv[8];
                #pragma unroll
                for (int q = 0; q < 8; ++q) xv[q] = xr[q];
                const float* wr0 = lds_w + (ab * 3 + c) * 3 * 33 + oc0;
                #pragma unroll
                for (int d = 0; d < 3; ++d) {
                    const float* wr = wr0 + d * 33;
                    const float w0 = wr[0], w1 = wr[1], w2 = wr[2], w3 = wr[3];
                    #pragma unroll
                    for (int q = 0; q < 6; ++q) {
                        const float xx = xv[q + d];
                        acc[0][q] = fmaf(xx, w0, acc[0][q]);
                        acc[1][q] = fmaf(xx, w1, acc[1][q]);
                        acc[2][q] = fmaf(xx, w2, acc[2][q]);
                        acc[3][q] = fmaf(xx, w3, acc[3][q]);
                    }
                }
            }
        }
    }

    if (active) {
        float* ob = out + (size_t)(n * 32 + oc0) * 104976
                        + i * 5832 + j * 324 + k * 18 + l0;
        #pragma unroll
        for (int u = 0; u < 4; ++u) {
            #pragma unroll
            for (int q = 0; q < 6; ++q)
                ob[u * 104976 + q] = acc[u][q];
        }
    }
}

extern "C" void kernel_launch(void* const* d_in, const int* in_sizes, int n_in,
                              void* d_out, int out_size, void* d_ws, size_t ws_size,
                              hipStream_t stream) {
    const float* x = (const float*)d_in[0];
    const float* w = (const float*)d_in[1];
    float* out = (float*)d_out;
    dim3 grid(18, 18, 2);
    conv4d_kernel<<<grid, BLK, 0, stream>>>(x, w, out);
}